// Round 3
// baseline (452.367 us; speedup 1.0000x reference)
//
#include <hip/hip_runtime.h>
#include <stdint.h>

typedef __bf16  bf16x8 __attribute__((ext_vector_type(8)));
typedef float   f32x4  __attribute__((ext_vector_type(4)));

__device__ __forceinline__ unsigned short f2bf(float f) {
  unsigned int u = __float_as_uint(f);
  u += 0x7fffu + ((u >> 16) & 1u);
  return (unsigned short)(u >> 16);
}
__device__ __forceinline__ float bflo(unsigned int v) { return __uint_as_float(v << 16); }
__device__ __forceinline__ float bfhi(unsigned int v) { return __uint_as_float(v & 0xffff0000u); }

// ---------- edge dtype detect (int64 vs int32): high words all zero => int64 ----------
__global__ void detect_fmt_kernel(const int* __restrict__ eg, int* __restrict__ fmt) {
  if (threadIdx.x == 0 && blockIdx.x == 0) {
    int is64 = 1;
    for (int i = 1; i < 32; i += 2) if (eg[i] != 0) { is64 = 0; break; }
    fmt[0] = is64;
  }
}

// ---------- fused: x->bf16 convert | weight prep | degree histogram ----------
__global__ void phase1_kernel(const float* __restrict__ x, unsigned short* __restrict__ A0, int n,
                              const int* __restrict__ eg, const int* __restrict__ fmt,
                              int* __restrict__ deg, int E,
                              const float* __restrict__ W00, const float* __restrict__ W10,
                              const float* __restrict__ W01, const float* __restrict__ W11,
                              const float* __restrict__ b00, const float* __restrict__ b10,
                              const float* __restrict__ b01, const float* __restrict__ b11,
                              unsigned short* __restrict__ Bt1, unsigned short* __restrict__ Bt2,
                              float* __restrict__ bias1, float* __restrict__ bias2) {
  const int i = blockIdx.x * 256 + threadIdx.x;
  if (i < n * 64) {
    const int row = i >> 6, c4 = i & 63;
    const float4 v = ((const float4*)x)[i];
    ushort4 o;
    o.x = f2bf(v.x); o.y = f2bf(v.y); o.z = f2bf(v.z); o.w = f2bf(v.w);
    *(ushort4*)&A0[(size_t)row * 512 + c4 * 4] = o;
  }
  if (i < 512 * 512) {
    const int nn = i >> 9, k = i & 511;
    const float v1 = (k < 256) ? W00[k * 512 + nn] : W10[(k - 256) * 512 + nn];
    Bt1[i] = f2bf(v1);
    const float v2 = (nn < 256) ? W01[k * 256 + nn] : W11[k * 256 + (nn - 256)];
    Bt2[i] = f2bf(v2);
    if (i < 512) {
      bias1[i] = b00[i] + b10[i];
      bias2[i] = (i < 256) ? (b01[i] + b11[i]) : 0.f;
    }
  }
  if (i < E) {
    int a, b;
    if (fmt[0]) { a = eg[4 * i]; b = eg[4 * i + 2]; }
    else        { a = eg[2 * i]; b = eg[2 * i + 1]; }
    if ((unsigned)a < (unsigned)n && (unsigned)b < (unsigned)n) {
      atomicAdd(&deg[a], 1);
      atomicAdd(&deg[b], 1);
    }
  }
}

// ---------- scan pass 1: per-block (1024) sums ----------
__global__ void block_sum_kernel(const int* __restrict__ deg, int* __restrict__ bsum, int n) {
  const int t = threadIdx.x;
  const int i = blockIdx.x * 1024 + t;
  int v = (i < n) ? deg[i] : 0;
  #pragma unroll
  for (int d = 32; d > 0; d >>= 1) v += __shfl_xor(v, d);
  __shared__ int ws[16];
  if ((t & 63) == 0) ws[t >> 6] = v;
  __syncthreads();
  if (t < 16) {
    int s = ws[t];
    #pragma unroll
    for (int d = 1; d < 16; d <<= 1) s += __shfl_xor(s, d);
    if (t == 0) bsum[blockIdx.x] = s;
  }
}

// ---------- scan pass 2: exclusive scan of block sums (<=64 blocks) ----------
__global__ void scan_bsum_kernel(int* __restrict__ bsum, int* __restrict__ off, int nb, int n) {
  const int l = threadIdx.x;
  int v = (l < nb) ? bsum[l] : 0;
  const int orig = v;
  #pragma unroll
  for (int d = 1; d < 64; d <<= 1) {
    int u = __shfl_up(v, d);
    if (l >= d) v += u;
  }
  if (l < nb) bsum[l] = v - orig;
  if (l == nb - 1) off[n] = v;
}

// ---------- scan pass 3: final offsets + invdeg + zero curp ----------
__global__ void scan_final_kernel(const int* __restrict__ deg, const int* __restrict__ bsum,
                                  int* __restrict__ off, float* __restrict__ invd,
                                  int* __restrict__ curp, int n) {
  const int t = threadIdx.x;
  const int i = blockIdx.x * 1024 + t;
  const int lane = t & 63, wid = t >> 6;
  const int v = (i < n) ? deg[i] : 0;
  int s = v;
  #pragma unroll
  for (int d = 1; d < 64; d <<= 1) {
    int u = __shfl_up(s, d);
    if (lane >= d) s += u;
  }
  __shared__ int ws[16];
  if (lane == 63) ws[wid] = s;
  __syncthreads();
  if (t < 16) {
    int w = ws[t];
    #pragma unroll
    for (int d = 1; d < 16; d <<= 1) {
      int u = __shfl_up(w, d);
      if (t >= d) w += u;
    }
    ws[t] = w;
  }
  __syncthreads();
  const int add = (wid > 0) ? ws[wid - 1] : 0;
  const int incl = s + add;
  if (i < n) {
    off[i] = bsum[blockIdx.x] + incl - v;
    invd[i] = 1.f / (float)(v > 1 ? v : 1);
    curp[i] = 0;
  }
}

// ---------- CSR fill ----------
__global__ void fill_kernel(const int* __restrict__ eg, const int* __restrict__ fmt,
                            const int* __restrict__ off, int* __restrict__ cur,
                            int* __restrict__ adj, int E, int n) {
  const int e = blockIdx.x * 256 + threadIdx.x;
  if (e >= E) return;
  int a, b;
  if (fmt[0]) { a = eg[4 * e]; b = eg[4 * e + 2]; }
  else        { a = eg[2 * e]; b = eg[2 * e + 1]; }
  if ((unsigned)a >= (unsigned)n || (unsigned)b >= (unsigned)n) return;
  int p = atomicAdd(&cur[b], 1); adj[off[b] + p] = a;
  int q = atomicAdd(&cur[a], 1); adj[off[a] + q] = b;
}

// ---------- XCD-sliced gathers ----------
// slice = blockIdx.x & 7 -> (round-robin dispatch) each XCD touches only a 3.2 MB
// column-slice of the gather table, which fits its 4 MiB L2. 8 lane-groups of 8
// gather 8 neighbors' 64B slices simultaneously; shfl_xor tree combines groups.

// agg0: mean of neighbor x (bf16, A0 left half) -> bf16 right half of A0
__global__ __launch_bounds__(256) void agg0_sliced_kernel(
    const unsigned short* A0r, unsigned short* A0w,
    const int* __restrict__ adj, const int* __restrict__ off,
    const float* __restrict__ invd, int n) {
  const int slice = blockIdx.x & 7;
  const int node = (blockIdx.x >> 3) * 4 + (threadIdx.x >> 6);
  if (node >= n) return;
  const int lane = threadIdx.x & 63;
  const int grp = lane >> 3;
  const int c0 = slice * 32 + (lane & 7) * 4;
  const int s = off[node], e = off[node + 1];
  float a0 = 0.f, a1 = 0.f, a2 = 0.f, a3 = 0.f;
  for (int base = s; base < e; base += 64) {
    const int cnt = min(64, e - base);
    const int idxv = (lane < cnt) ? adj[base + lane] : 0;
    const int jmax = (cnt + 7) >> 3;
    int j = 0;
    for (; j + 2 <= jmax; j += 2) {
      const int s0 = j * 8 + grp, s1 = s0 + 8;
      const int p0 = __shfl(idxv, s0), p1 = __shfl(idxv, s1);
      uint2 v0 = make_uint2(0u, 0u), v1 = make_uint2(0u, 0u);
      if (s0 < cnt) v0 = *(const uint2*)&A0r[(size_t)p0 * 512 + c0];
      if (s1 < cnt) v1 = *(const uint2*)&A0r[(size_t)p1 * 512 + c0];
      a0 += bflo(v0.x) + bflo(v1.x); a1 += bfhi(v0.x) + bfhi(v1.x);
      a2 += bflo(v0.y) + bflo(v1.y); a3 += bfhi(v0.y) + bfhi(v1.y);
    }
    for (; j < jmax; ++j) {
      const int s0 = j * 8 + grp;
      const int p0 = __shfl(idxv, s0);
      uint2 v0 = make_uint2(0u, 0u);
      if (s0 < cnt) v0 = *(const uint2*)&A0r[(size_t)p0 * 512 + c0];
      a0 += bflo(v0.x); a1 += bfhi(v0.x);
      a2 += bflo(v0.y); a3 += bfhi(v0.y);
    }
  }
  #pragma unroll
  for (int d = 8; d < 64; d <<= 1) {
    a0 += __shfl_xor(a0, d); a1 += __shfl_xor(a1, d);
    a2 += __shfl_xor(a2, d); a3 += __shfl_xor(a3, d);
  }
  if (grp == 0) {
    const float sc = invd[node];
    ushort4 o;
    o.x = f2bf(a0 * sc); o.y = f2bf(a1 * sc); o.z = f2bf(a2 * sc); o.w = f2bf(a3 * sc);
    *(ushort4*)&A0w[(size_t)node * 512 + 256 + c0] = o;
  }
}

// out += invdeg * sum of neighbor z (bf16); out already holds the self path P
__global__ __launch_bounds__(256) void agg_out_sliced_kernel(
    const unsigned short* __restrict__ Z, float* out,
    const int* __restrict__ adj, const int* __restrict__ off,
    const float* __restrict__ invd, int n) {
  const int slice = blockIdx.x & 7;
  const int node = (blockIdx.x >> 3) * 4 + (threadIdx.x >> 6);
  if (node >= n) return;
  const int lane = threadIdx.x & 63;
  const int grp = lane >> 3;
  const int c0 = slice * 32 + (lane & 7) * 4;
  const int s = off[node], e = off[node + 1];
  float a0 = 0.f, a1 = 0.f, a2 = 0.f, a3 = 0.f;
  for (int base = s; base < e; base += 64) {
    const int cnt = min(64, e - base);
    const int idxv = (lane < cnt) ? adj[base + lane] : 0;
    const int jmax = (cnt + 7) >> 3;
    int j = 0;
    for (; j + 2 <= jmax; j += 2) {
      const int s0 = j * 8 + grp, s1 = s0 + 8;
      const int p0 = __shfl(idxv, s0), p1 = __shfl(idxv, s1);
      uint2 v0 = make_uint2(0u, 0u), v1 = make_uint2(0u, 0u);
      if (s0 < cnt) v0 = *(const uint2*)&Z[(size_t)p0 * 256 + c0];
      if (s1 < cnt) v1 = *(const uint2*)&Z[(size_t)p1 * 256 + c0];
      a0 += bflo(v0.x) + bflo(v1.x); a1 += bfhi(v0.x) + bfhi(v1.x);
      a2 += bflo(v0.y) + bflo(v1.y); a3 += bfhi(v0.y) + bfhi(v1.y);
    }
    for (; j < jmax; ++j) {
      const int s0 = j * 8 + grp;
      const int p0 = __shfl(idxv, s0);
      uint2 v0 = make_uint2(0u, 0u);
      if (s0 < cnt) v0 = *(const uint2*)&Z[(size_t)p0 * 256 + c0];
      a0 += bflo(v0.x); a1 += bfhi(v0.x);
      a2 += bflo(v0.y); a3 += bfhi(v0.y);
    }
  }
  #pragma unroll
  for (int d = 8; d < 64; d <<= 1) {
    a0 += __shfl_xor(a0, d); a1 += __shfl_xor(a1, d);
    a2 += __shfl_xor(a2, d); a3 += __shfl_xor(a3, d);
  }
  if (grp == 0) {
    const float sc = invd[node];
    float4* po = (float4*)&out[(size_t)node * 256 + c0];
    float4 o = *po;
    o.x += sc * a0; o.y += sc * a1; o.z += sc * a2; o.w += sc * a3;
    *po = o;
  }
}

// ---------- bf16 MFMA GEMM: C[M,512] = A[M,512] @ B[512,512]; B given as Bt[n][k] ----------
// BK=32 double-buffered (32 KiB LDS -> 4 blocks/CU). LDS swizzle: chunk ^= (row>>1)&3
// applied to BOTH the pre-swizzled global source and the ds_read address (involution).
// Epilogue repacks C through LDS (bank-XOR) for coalesced 16B stores.
// MODE 0: Hout = bf16(relu(C + bias[col]))
// MODE 1: n0<256 -> Pout fp32 = C + bias[col] (row<M guard); else Zout = bf16(C)
template<int MODE>
__global__ __launch_bounds__(256, 4) void gemm_kernel(
    const unsigned short* __restrict__ A, const unsigned short* __restrict__ Bt,
    const float* __restrict__ bias,
    unsigned short* __restrict__ Hout, float* __restrict__ Pout, unsigned short* __restrict__ Zout,
    int M_real, int nwg) {
  constexpr int K = 512;
  constexpr int BK = 32;
  __shared__ unsigned short sm[4][128 * BK];
  const int t = threadIdx.x;
  const int lane = t & 63;
  const int wid = t >> 6;
  const int wr = wid >> 1;
  const int wc = wid & 1;

  const int orig = blockIdx.x;
  const int q = nwg >> 3, r = nwg & 7;
  const int xcd = orig & 7, bidx = orig >> 3;
  const int wgid = (xcd < r ? xcd * (q + 1) : r * (q + 1) + (xcd - r) * q) + bidx;
  const int m0 = (wgid >> 2) * 128;
  const int n0 = (wgid & 3) * 128;

  f32x4 acc[4][4];
  #pragma unroll
  for (int m = 0; m < 4; ++m)
    #pragma unroll
    for (int n = 0; n < 4; ++n)
      acc[m][n] = f32x4{0.f, 0.f, 0.f, 0.f};

  auto stage = [&](int buf, int kt) {
    #pragma unroll
    for (int i = 0; i < 2; ++i) {
      const int row = i * 64 + (t >> 2);
      const int c = (t & 3) ^ ((row >> 1) & 3);
      const unsigned short* ga = A + (size_t)(m0 + row) * K + kt * BK + c * 8;
      __builtin_amdgcn_global_load_lds(
          (const __attribute__((address_space(1))) unsigned int*)ga,
          (__attribute__((address_space(3))) unsigned int*)&sm[buf][(i * 256 + t) * 8], 16, 0, 0);
    }
    #pragma unroll
    for (int i = 0; i < 2; ++i) {
      const int row = i * 64 + (t >> 2);
      const int c = (t & 3) ^ ((row >> 1) & 3);
      const unsigned short* gb = Bt + (size_t)(n0 + row) * K + kt * BK + c * 8;
      __builtin_amdgcn_global_load_lds(
          (const __attribute__((address_space(1))) unsigned int*)gb,
          (__attribute__((address_space(3))) unsigned int*)&sm[2 + buf][(i * 256 + t) * 8], 16, 0, 0);
    }
  };

  auto compute = [&](int buf) {
    bf16x8 aF[4], bF[4];
    #pragma unroll
    for (int m = 0; m < 4; ++m) {
      const int row = wr * 64 + m * 16 + (lane & 15);
      const int sl = (lane >> 4) ^ ((row >> 1) & 3);
      aF[m] = *(const bf16x8*)&sm[buf][row * BK + sl * 8];
    }
    #pragma unroll
    for (int n = 0; n < 4; ++n) {
      const int row = wc * 64 + n * 16 + (lane & 15);
      const int sl = (lane >> 4) ^ ((row >> 1) & 3);
      bF[n] = *(const bf16x8*)&sm[2 + buf][row * BK + sl * 8];
    }
    #pragma unroll
    for (int m = 0; m < 4; ++m)
      #pragma unroll
      for (int n = 0; n < 4; ++n)
        acc[m][n] = __builtin_amdgcn_mfma_f32_16x16x32_bf16(aF[m], bF[n], acc[m][n], 0, 0, 0);
  };

  stage(0, 0);
  __syncthreads();
  int cur = 0;
  #pragma unroll 1
  for (int kt = 0; kt < K / BK - 1; ++kt) {
    stage(cur ^ 1, kt + 1);
    compute(cur);
    __syncthreads();
    cur ^= 1;
  }
  compute(cur);
  __syncthreads();

  if (MODE == 0 || n0 >= 256) {
    unsigned short* ep = &sm[0][0];
    #pragma unroll
    for (int n = 0; n < 4; ++n) {
      const int lcol = wc * 64 + n * 16 + (lane & 15);
      const float bc = (MODE == 0) ? bias[n0 + lcol] : 0.f;
      #pragma unroll
      for (int m = 0; m < 4; ++m) {
        #pragma unroll
        for (int rr = 0; rr < 4; ++rr) {
          const int lr = wr * 64 + m * 16 + (lane >> 4) * 4 + rr;
          float y = acc[m][n][rr] + bc;
          if (MODE == 0) y = y > 0.f ? y : 0.f;
          ep[lr * 128 + (lcol ^ (((lr >> 2) & 7) << 4))] = f2bf(y);
        }
      }
    }
    __syncthreads();
    unsigned short* dst = (MODE == 0) ? Hout : Zout;
    const int ld = (MODE == 0) ? 512 : 256;
    const int cb0 = (MODE == 0) ? n0 : (n0 - 256);
    #pragma unroll
    for (int p = 0; p < 8; ++p) {
      const int tr = p * 16 + (t >> 4);
      const int cb = (t & 15) * 8;
      const uint4 v = *(const uint4*)&ep[tr * 128 + (cb ^ (((tr >> 2) & 7) << 4))];
      *(uint4*)&dst[(size_t)(m0 + tr) * ld + cb0 + cb] = v;
    }
  } else {
    float* ep = (float*)&sm[0][0];
    #pragma unroll
    for (int pp = 0; pp < 2; ++pp) {
      if (wr == pp) {
        #pragma unroll
        for (int n = 0; n < 4; ++n) {
          const int lcol = wc * 64 + n * 16 + (lane & 15);
          const float bc = bias[n0 + lcol];
          #pragma unroll
          for (int m = 0; m < 4; ++m)
            #pragma unroll
            for (int rr = 0; rr < 4; ++rr) {
              const int lr = m * 16 + (lane >> 4) * 4 + rr;
              ep[lr * 128 + (lcol ^ (((lr >> 2) & 7) << 4))] = acc[m][n][rr] + bc;
            }
        }
      }
      __syncthreads();
      const int tr = t >> 2;
      const int grow = m0 + pp * 64 + tr;
      if (grow < M_real) {
        #pragma unroll
        for (int j = 0; j < 8; ++j) {
          const int cb = (t & 3) * 32 + j * 4;
          const float4 v = *(const float4*)&ep[tr * 128 + (cb ^ (((tr >> 2) & 7) << 4))];
          *(float4*)&Pout[(size_t)grow * 256 + n0 + cb] = v;
        }
      }
      __syncthreads();
    }
  }
}

extern "C" void kernel_launch(void* const* d_in, const int* in_sizes, int n_in,
                              void* d_out, int out_size, void* d_ws, size_t ws_size,
                              hipStream_t stream) {
  const float* x   = (const float*)d_in[0];
  const int* edges = (const int*)d_in[1];
  const float* W00 = (const float*)d_in[2];
  const float* b00 = (const float*)d_in[3];
  const float* W10 = (const float*)d_in[4];
  const float* b10 = (const float*)d_in[5];
  const float* W01 = (const float*)d_in[6];
  const float* b01 = (const float*)d_in[7];
  const float* W11 = (const float*)d_in[8];
  const float* b11 = (const float*)d_in[9];
  float* out = (float*)d_out;

  const int n = in_sizes[0] / 256;   // 50000 nodes
  const int E = in_sizes[1] / 2;     // 400000 edges
  const int Mpad = ((n + 127) / 128) * 128;

  char* p = (char*)d_ws;
  auto alloc = [&](size_t bytes) { char* r = p; p += (bytes + 255) & ~(size_t)255; return r; };
  unsigned short* A0   = (unsigned short*)alloc((size_t)Mpad * 512 * 2);
  unsigned short* H    = (unsigned short*)alloc((size_t)Mpad * 512 * 2);
  unsigned short* Z    = (unsigned short*)alloc((size_t)Mpad * 256 * 2);
  unsigned short* Bt1  = (unsigned short*)alloc(512 * 512 * 2);
  unsigned short* Bt2  = (unsigned short*)alloc(512 * 512 * 2);
  float* bias1 = (float*)alloc(512 * 4);
  float* bias2 = (float*)alloc(512 * 4);
  int*   deg   = (int*)alloc((size_t)n * 4);
  int*   curp  = (int*)alloc((size_t)n * 4);
  int*   off   = (int*)alloc((size_t)(n + 1) * 4);
  int*   bsum  = (int*)alloc(256 * 4);
  float* invd  = (float*)alloc((size_t)n * 4);
  int*   adj   = (int*)alloc((size_t)2 * E * 4);
  int*   fmt   = (int*)alloc(256);

  hipMemsetAsync(deg, 0, (size_t)n * 4, stream);

  detect_fmt_kernel<<<1, 64, 0, stream>>>(edges, fmt);

  const int p1_blocks = (n * 64 + 255) / 256;
  phase1_kernel<<<p1_blocks, 256, 0, stream>>>(x, A0, n, edges, fmt, deg, E,
                                               W00, W10, W01, W11, b00, b10, b01, b11,
                                               Bt1, Bt2, bias1, bias2);

  const int nb = (n + 1023) / 1024;
  block_sum_kernel<<<nb, 1024, 0, stream>>>(deg, bsum, n);
  scan_bsum_kernel<<<1, 64, 0, stream>>>(bsum, off, nb, n);
  scan_final_kernel<<<nb, 1024, 0, stream>>>(deg, bsum, off, invd, curp, n);
  fill_kernel<<<(E + 255) / 256, 256, 0, stream>>>(edges, fmt, off, curp, adj, E, n);

  const int agg_blocks = 8 * ((n + 3) / 4);
  agg0_sliced_kernel<<<agg_blocks, 256, 0, stream>>>(A0, A0, adj, off, invd, n);

  const int nwg = (Mpad / 128) * 4;
  gemm_kernel<0><<<nwg, 256, 0, stream>>>(A0, Bt1, bias1, H, nullptr, nullptr, n, nwg);
  gemm_kernel<1><<<nwg, 256, 0, stream>>>(H, Bt2, bias2, nullptr, out, Z, n, nwg);

  agg_out_sliced_kernel<<<agg_blocks, 256, 0, stream>>>(Z, out, adj, off, invd, n);
}

// Round 4
// 320.399 us; speedup vs baseline: 1.4119x; 1.4119x over previous
//
#include <hip/hip_runtime.h>
#include <stdint.h>

typedef __bf16  bf16x8 __attribute__((ext_vector_type(8)));
typedef float   f32x4  __attribute__((ext_vector_type(4)));
typedef unsigned short u16x8 __attribute__((ext_vector_type(8)));

__device__ __forceinline__ unsigned short f2bf(float f) {
  unsigned int u = __float_as_uint(f);
  u += 0x7fffu + ((u >> 16) & 1u);
  return (unsigned short)(u >> 16);
}
__device__ __forceinline__ float bflo(unsigned int v) { return __uint_as_float(v << 16); }
__device__ __forceinline__ float bfhi(unsigned int v) { return __uint_as_float(v & 0xffff0000u); }

// ---------- edge dtype detect (int64 vs int32): high words all zero => int64 ----------
__global__ void detect_fmt_kernel(const int* __restrict__ eg, int* __restrict__ fmt) {
  if (threadIdx.x == 0 && blockIdx.x == 0) {
    int is64 = 1;
    for (int i = 1; i < 32; i += 2) if (eg[i] != 0) { is64 = 0; break; }
    fmt[0] = is64;
  }
}

// ---------- fused: x->bf16 convert | weight prep | degree histogram ----------
__global__ void phase1_kernel(const float* __restrict__ x, unsigned short* __restrict__ A0, int n,
                              const int* __restrict__ eg, const int* __restrict__ fmt,
                              int* __restrict__ deg, int E,
                              const float* __restrict__ W00, const float* __restrict__ W10,
                              const float* __restrict__ W01, const float* __restrict__ W11,
                              const float* __restrict__ b00, const float* __restrict__ b10,
                              const float* __restrict__ b01, const float* __restrict__ b11,
                              unsigned short* __restrict__ Bt1, unsigned short* __restrict__ Bt2,
                              float* __restrict__ bias1, float* __restrict__ bias2) {
  const int i = blockIdx.x * 256 + threadIdx.x;
  if (i < n * 64) {
    const int row = i >> 6, c4 = i & 63;
    const float4 v = ((const float4*)x)[i];
    ushort4 o;
    o.x = f2bf(v.x); o.y = f2bf(v.y); o.z = f2bf(v.z); o.w = f2bf(v.w);
    *(ushort4*)&A0[(size_t)row * 512 + c4 * 4] = o;
  }
  if (i < 512 * 512) {
    const int nn = i >> 9, k = i & 511;
    const float v1 = (k < 256) ? W00[k * 512 + nn] : W10[(k - 256) * 512 + nn];
    Bt1[i] = f2bf(v1);
    const float v2 = (nn < 256) ? W01[k * 256 + nn] : W11[k * 256 + (nn - 256)];
    Bt2[i] = f2bf(v2);
    if (i < 512) {
      bias1[i] = b00[i] + b10[i];
      bias2[i] = (i < 256) ? (b01[i] + b11[i]) : 0.f;
    }
  }
  if (i < E) {
    int a, b;
    if (fmt[0]) { a = eg[4 * i]; b = eg[4 * i + 2]; }
    else        { a = eg[2 * i]; b = eg[2 * i + 1]; }
    if ((unsigned)a < (unsigned)n && (unsigned)b < (unsigned)n) {
      atomicAdd(&deg[a], 1);
      atomicAdd(&deg[b], 1);
    }
  }
}

// ---------- scan pass 1: per-block (1024) sums ----------
__global__ void block_sum_kernel(const int* __restrict__ deg, int* __restrict__ bsum, int n) {
  const int t = threadIdx.x;
  const int i = blockIdx.x * 1024 + t;
  int v = (i < n) ? deg[i] : 0;
  #pragma unroll
  for (int d = 32; d > 0; d >>= 1) v += __shfl_xor(v, d);
  __shared__ int ws[16];
  if ((t & 63) == 0) ws[t >> 6] = v;
  __syncthreads();
  if (t < 16) {
    int s = ws[t];
    #pragma unroll
    for (int d = 1; d < 16; d <<= 1) s += __shfl_xor(s, d);
    if (t == 0) bsum[blockIdx.x] = s;
  }
}

// ---------- scan pass 2: exclusive scan of block sums (<=64 blocks) ----------
__global__ void scan_bsum_kernel(int* __restrict__ bsum, int* __restrict__ off, int nb, int n) {
  const int l = threadIdx.x;
  int v = (l < nb) ? bsum[l] : 0;
  const int orig = v;
  #pragma unroll
  for (int d = 1; d < 64; d <<= 1) {
    int u = __shfl_up(v, d);
    if (l >= d) v += u;
  }
  if (l < nb) bsum[l] = v - orig;
  if (l == nb - 1) off[n] = v;
}

// ---------- scan pass 3: final offsets + invdeg + zero curp ----------
__global__ void scan_final_kernel(const int* __restrict__ deg, const int* __restrict__ bsum,
                                  int* __restrict__ off, float* __restrict__ invd,
                                  int* __restrict__ curp, int n) {
  const int t = threadIdx.x;
  const int i = blockIdx.x * 1024 + t;
  const int lane = t & 63, wid = t >> 6;
  const int v = (i < n) ? deg[i] : 0;
  int s = v;
  #pragma unroll
  for (int d = 1; d < 64; d <<= 1) {
    int u = __shfl_up(s, d);
    if (lane >= d) s += u;
  }
  __shared__ int ws[16];
  if (lane == 63) ws[wid] = s;
  __syncthreads();
  if (t < 16) {
    int w = ws[t];
    #pragma unroll
    for (int d = 1; d < 16; d <<= 1) {
      int u = __shfl_up(w, d);
      if (t >= d) w += u;
    }
    ws[t] = w;
  }
  __syncthreads();
  const int add = (wid > 0) ? ws[wid - 1] : 0;
  const int incl = s + add;
  if (i < n) {
    off[i] = bsum[blockIdx.x] + incl - v;
    invd[i] = 1.f / (float)(v > 1 ? v : 1);
    curp[i] = 0;
  }
}

// ---------- CSR fill ----------
__global__ void fill_kernel(const int* __restrict__ eg, const int* __restrict__ fmt,
                            const int* __restrict__ off, int* __restrict__ cur,
                            int* __restrict__ adj, int E, int n) {
  const int e = blockIdx.x * 256 + threadIdx.x;
  if (e >= E) return;
  int a, b;
  if (fmt[0]) { a = eg[4 * e]; b = eg[4 * e + 2]; }
  else        { a = eg[2 * e]; b = eg[2 * e + 1]; }
  if ((unsigned)a >= (unsigned)n || (unsigned)b >= (unsigned)n) return;
  int p = atomicAdd(&cur[b], 1); adj[off[b] + p] = a;
  int q = atomicAdd(&cur[a], 1); adj[off[a] + q] = b;
}

// ---------- wide gather: one wave per dst node; 2 neighbor rows per uint4 load ----------
// lane l: half = l>>5 selects which of 2 rows, cq = l&31 selects the 16B chunk
// (32 lanes x 16B = full 512B row). 4 loads in flight cover 8 neighbors (4KB/wave).
// Halves combined with shfl_xor(·,32); lanes 0-31 write the 512B result row.
// MODE 0: A0 left half (stride 512) -> bf16 mean into A0 right half
// MODE 1: Z (stride 256) -> out += invd * sum (fp32 RMW; out holds self path P)
template<int MODE>
__global__ __launch_bounds__(256) void agg_wide_kernel(
    const unsigned short* __restrict__ T, unsigned short* A0w, float* out,
    const int* __restrict__ adj, const int* __restrict__ off,
    const float* __restrict__ invd, int n) {
  const int node = blockIdx.x * 4 + (threadIdx.x >> 6);
  if (node >= n) return;
  const int lane = threadIdx.x & 63;
  const int half = lane >> 5;
  const int cq = lane & 31;
  constexpr size_t RS = (MODE == 0) ? 512 : 256;
  const int s = off[node], e = off[node + 1];
  float a0 = 0.f, a1 = 0.f, a2 = 0.f, a3 = 0.f, a4 = 0.f, a5 = 0.f, a6 = 0.f, a7 = 0.f;
  for (int base = s; base < e; base += 64) {
    const int cnt = min(64, e - base);
    const int idxv = (lane < cnt) ? adj[base + lane] : 0;
    for (int j = 0; j < cnt; j += 8) {
      uint4 v0 = make_uint4(0u, 0u, 0u, 0u), v1 = v0, v2 = v0, v3 = v0;
      const int s0 = j + 0 + half, s1 = j + 2 + half, s2 = j + 4 + half, s3 = j + 6 + half;
      const int r0 = __shfl(idxv, s0), r1 = __shfl(idxv, s1);
      const int r2 = __shfl(idxv, s2), r3 = __shfl(idxv, s3);
      if (s0 < cnt) v0 = *(const uint4*)&T[(size_t)r0 * RS + cq * 8];
      if (s1 < cnt) v1 = *(const uint4*)&T[(size_t)r1 * RS + cq * 8];
      if (s2 < cnt) v2 = *(const uint4*)&T[(size_t)r2 * RS + cq * 8];
      if (s3 < cnt) v3 = *(const uint4*)&T[(size_t)r3 * RS + cq * 8];
      a0 += bflo(v0.x) + bflo(v1.x) + bflo(v2.x) + bflo(v3.x);
      a1 += bfhi(v0.x) + bfhi(v1.x) + bfhi(v2.x) + bfhi(v3.x);
      a2 += bflo(v0.y) + bflo(v1.y) + bflo(v2.y) + bflo(v3.y);
      a3 += bfhi(v0.y) + bfhi(v1.y) + bfhi(v2.y) + bfhi(v3.y);
      a4 += bflo(v0.z) + bflo(v1.z) + bflo(v2.z) + bflo(v3.z);
      a5 += bfhi(v0.z) + bfhi(v1.z) + bfhi(v2.z) + bfhi(v3.z);
      a6 += bflo(v0.w) + bflo(v1.w) + bflo(v2.w) + bflo(v3.w);
      a7 += bfhi(v0.w) + bfhi(v1.w) + bfhi(v2.w) + bfhi(v3.w);
    }
  }
  a0 += __shfl_xor(a0, 32); a1 += __shfl_xor(a1, 32);
  a2 += __shfl_xor(a2, 32); a3 += __shfl_xor(a3, 32);
  a4 += __shfl_xor(a4, 32); a5 += __shfl_xor(a5, 32);
  a6 += __shfl_xor(a6, 32); a7 += __shfl_xor(a7, 32);
  if (half == 0) {
    const float sc = invd[node];
    if (MODE == 0) {
      u16x8 o;
      o[0] = f2bf(a0 * sc); o[1] = f2bf(a1 * sc); o[2] = f2bf(a2 * sc); o[3] = f2bf(a3 * sc);
      o[4] = f2bf(a4 * sc); o[5] = f2bf(a5 * sc); o[6] = f2bf(a6 * sc); o[7] = f2bf(a7 * sc);
      *(u16x8*)&A0w[(size_t)node * 512 + 256 + cq * 8] = o;
    } else {
      float* po = &out[(size_t)node * 256 + cq * 8];
      float4 p0 = *(float4*)po;
      float4 p1 = *(float4*)(po + 4);
      p0.x += sc * a0; p0.y += sc * a1; p0.z += sc * a2; p0.w += sc * a3;
      p1.x += sc * a4; p1.y += sc * a5; p1.z += sc * a6; p1.w += sc * a7;
      *(float4*)po = p0;
      *(float4*)(po + 4) = p1;
    }
  }
}

// ---------- bf16 MFMA GEMM: C[M,512] = A[M,512] @ B[512,512]; B given as Bt[n][k] ----------
// BK=32 double-buffered (32 KiB LDS -> 4 blocks/CU). LDS swizzle: chunk ^= (row>>1)&3
// applied to BOTH the pre-swizzled global source and the ds_read address (involution).
// Epilogue repacks C through LDS (bank-XOR) for coalesced 16B stores.
// MODE 0: Hout = bf16(relu(C + bias[col]))
// MODE 1: n0<256 -> Pout fp32 = C + bias[col] (row<M guard); else Zout = bf16(C)
template<int MODE>
__global__ __launch_bounds__(256, 4) void gemm_kernel(
    const unsigned short* __restrict__ A, const unsigned short* __restrict__ Bt,
    const float* __restrict__ bias,
    unsigned short* __restrict__ Hout, float* __restrict__ Pout, unsigned short* __restrict__ Zout,
    int M_real, int nwg) {
  constexpr int K = 512;
  constexpr int BK = 32;
  __shared__ unsigned short sm[4][128 * BK];
  const int t = threadIdx.x;
  const int lane = t & 63;
  const int wid = t >> 6;
  const int wr = wid >> 1;
  const int wc = wid & 1;

  const int orig = blockIdx.x;
  const int q = nwg >> 3, r = nwg & 7;
  const int xcd = orig & 7, bidx = orig >> 3;
  const int wgid = (xcd < r ? xcd * (q + 1) : r * (q + 1) + (xcd - r) * q) + bidx;
  const int m0 = (wgid >> 2) * 128;
  const int n0 = (wgid & 3) * 128;

  f32x4 acc[4][4];
  #pragma unroll
  for (int m = 0; m < 4; ++m)
    #pragma unroll
    for (int n = 0; n < 4; ++n)
      acc[m][n] = f32x4{0.f, 0.f, 0.f, 0.f};

  auto stage = [&](int buf, int kt) {
    #pragma unroll
    for (int i = 0; i < 2; ++i) {
      const int row = i * 64 + (t >> 2);
      const int c = (t & 3) ^ ((row >> 1) & 3);
      const unsigned short* ga = A + (size_t)(m0 + row) * K + kt * BK + c * 8;
      __builtin_amdgcn_global_load_lds(
          (const __attribute__((address_space(1))) unsigned int*)ga,
          (__attribute__((address_space(3))) unsigned int*)&sm[buf][(i * 256 + t) * 8], 16, 0, 0);
    }
    #pragma unroll
    for (int i = 0; i < 2; ++i) {
      const int row = i * 64 + (t >> 2);
      const int c = (t & 3) ^ ((row >> 1) & 3);
      const unsigned short* gb = Bt + (size_t)(n0 + row) * K + kt * BK + c * 8;
      __builtin_amdgcn_global_load_lds(
          (const __attribute__((address_space(1))) unsigned int*)gb,
          (__attribute__((address_space(3))) unsigned int*)&sm[2 + buf][(i * 256 + t) * 8], 16, 0, 0);
    }
  };

  auto compute = [&](int buf) {
    bf16x8 aF[4], bF[4];
    #pragma unroll
    for (int m = 0; m < 4; ++m) {
      const int row = wr * 64 + m * 16 + (lane & 15);
      const int sl = (lane >> 4) ^ ((row >> 1) & 3);
      aF[m] = *(const bf16x8*)&sm[buf][row * BK + sl * 8];
    }
    #pragma unroll
    for (int n = 0; n < 4; ++n) {
      const int row = wc * 64 + n * 16 + (lane & 15);
      const int sl = (lane >> 4) ^ ((row >> 1) & 3);
      bF[n] = *(const bf16x8*)&sm[2 + buf][row * BK + sl * 8];
    }
    #pragma unroll
    for (int m = 0; m < 4; ++m)
      #pragma unroll
      for (int n = 0; n < 4; ++n)
        acc[m][n] = __builtin_amdgcn_mfma_f32_16x16x32_bf16(aF[m], bF[n], acc[m][n], 0, 0, 0);
  };

  stage(0, 0);
  __syncthreads();
  int cur = 0;
  #pragma unroll 1
  for (int kt = 0; kt < K / BK - 1; ++kt) {
    stage(cur ^ 1, kt + 1);
    compute(cur);
    __syncthreads();
    cur ^= 1;
  }
  compute(cur);
  __syncthreads();

  if (MODE == 0 || n0 >= 256) {
    unsigned short* ep = &sm[0][0];
    #pragma unroll
    for (int n = 0; n < 4; ++n) {
      const int lcol = wc * 64 + n * 16 + (lane & 15);
      const float bc = (MODE == 0) ? bias[n0 + lcol] : 0.f;
      #pragma unroll
      for (int m = 0; m < 4; ++m) {
        #pragma unroll
        for (int rr = 0; rr < 4; ++rr) {
          const int lr = wr * 64 + m * 16 + (lane >> 4) * 4 + rr;
          float y = acc[m][n][rr] + bc;
          if (MODE == 0) y = y > 0.f ? y : 0.f;
          ep[lr * 128 + (lcol ^ (((lr >> 2) & 7) << 4))] = f2bf(y);
        }
      }
    }
    __syncthreads();
    unsigned short* dst = (MODE == 0) ? Hout : Zout;
    const int ld = (MODE == 0) ? 512 : 256;
    const int cb0 = (MODE == 0) ? n0 : (n0 - 256);
    #pragma unroll
    for (int p = 0; p < 8; ++p) {
      const int tr = p * 16 + (t >> 4);
      const int cb = (t & 15) * 8;
      const uint4 v = *(const uint4*)&ep[tr * 128 + (cb ^ (((tr >> 2) & 7) << 4))];
      *(uint4*)&dst[(size_t)(m0 + tr) * ld + cb0 + cb] = v;
    }
  } else {
    float* ep = (float*)&sm[0][0];
    #pragma unroll
    for (int pp = 0; pp < 2; ++pp) {
      if (wr == pp) {
        #pragma unroll
        for (int n = 0; n < 4; ++n) {
          const int lcol = wc * 64 + n * 16 + (lane & 15);
          const float bc = bias[n0 + lcol];
          #pragma unroll
          for (int m = 0; m < 4; ++m)
            #pragma unroll
            for (int rr = 0; rr < 4; ++rr) {
              const int lr = m * 16 + (lane >> 4) * 4 + rr;
              ep[lr * 128 + (lcol ^ (((lr >> 2) & 7) << 4))] = acc[m][n][rr] + bc;
            }
        }
      }
      __syncthreads();
      const int tr = t >> 2;
      const int grow = m0 + pp * 64 + tr;
      if (grow < M_real) {
        #pragma unroll
        for (int j = 0; j < 8; ++j) {
          const int cb = (t & 3) * 32 + j * 4;
          const float4 v = *(const float4*)&ep[tr * 128 + (cb ^ (((tr >> 2) & 7) << 4))];
          *(float4*)&Pout[(size_t)grow * 256 + n0 + cb] = v;
        }
      }
      __syncthreads();
    }
  }
}

extern "C" void kernel_launch(void* const* d_in, const int* in_sizes, int n_in,
                              void* d_out, int out_size, void* d_ws, size_t ws_size,
                              hipStream_t stream) {
  const float* x   = (const float*)d_in[0];
  const int* edges = (const int*)d_in[1];
  const float* W00 = (const float*)d_in[2];
  const float* b00 = (const float*)d_in[3];
  const float* W10 = (const float*)d_in[4];
  const float* b10 = (const float*)d_in[5];
  const float* W01 = (const float*)d_in[6];
  const float* b01 = (const float*)d_in[7];
  const float* W11 = (const float*)d_in[8];
  const float* b11 = (const float*)d_in[9];
  float* out = (float*)d_out;

  const int n = in_sizes[0] / 256;   // 50000 nodes
  const int E = in_sizes[1] / 2;     // 400000 edges
  const int Mpad = ((n + 127) / 128) * 128;

  char* p = (char*)d_ws;
  auto alloc = [&](size_t bytes) { char* r = p; p += (bytes + 255) & ~(size_t)255; return r; };
  unsigned short* A0   = (unsigned short*)alloc((size_t)Mpad * 512 * 2);
  unsigned short* H    = (unsigned short*)alloc((size_t)Mpad * 512 * 2);
  unsigned short* Z    = (unsigned short*)alloc((size_t)Mpad * 256 * 2);
  unsigned short* Bt1  = (unsigned short*)alloc(512 * 512 * 2);
  unsigned short* Bt2  = (unsigned short*)alloc(512 * 512 * 2);
  float* bias1 = (float*)alloc(512 * 4);
  float* bias2 = (float*)alloc(512 * 4);
  int*   deg   = (int*)alloc((size_t)n * 4);
  int*   curp  = (int*)alloc((size_t)n * 4);
  int*   off   = (int*)alloc((size_t)(n + 1) * 4);
  int*   bsum  = (int*)alloc(256 * 4);
  float* invd  = (float*)alloc((size_t)n * 4);
  int*   adj   = (int*)alloc((size_t)2 * E * 4);
  int*   fmt   = (int*)alloc(256);

  hipMemsetAsync(deg, 0, (size_t)n * 4, stream);

  detect_fmt_kernel<<<1, 64, 0, stream>>>(edges, fmt);

  const int p1_blocks = (n * 64 + 255) / 256;
  phase1_kernel<<<p1_blocks, 256, 0, stream>>>(x, A0, n, edges, fmt, deg, E,
                                               W00, W10, W01, W11, b00, b10, b01, b11,
                                               Bt1, Bt2, bias1, bias2);

  const int nb = (n + 1023) / 1024;
  block_sum_kernel<<<nb, 1024, 0, stream>>>(deg, bsum, n);
  scan_bsum_kernel<<<1, 64, 0, stream>>>(bsum, off, nb, n);
  scan_final_kernel<<<nb, 1024, 0, stream>>>(deg, bsum, off, invd, curp, n);
  fill_kernel<<<(E + 255) / 256, 256, 0, stream>>>(edges, fmt, off, curp, adj, E, n);

  agg_wide_kernel<0><<<(n + 3) / 4, 256, 0, stream>>>(A0, A0, nullptr, adj, off, invd, n);

  const int nwg = (Mpad / 128) * 4;
  gemm_kernel<0><<<nwg, 256, 0, stream>>>(A0, Bt1, bias1, H, nullptr, nullptr, n, nwg);
  gemm_kernel<1><<<nwg, 256, 0, stream>>>(H, Bt2, bias2, nullptr, out, Z, n, nwg);

  agg_wide_kernel<1><<<(n + 3) / 4, 256, 0, stream>>>(Z, nullptr, out, adj, off, invd, n);
}

// Round 6
// 320.059 us; speedup vs baseline: 1.4134x; 1.0011x over previous
//
#include <hip/hip_runtime.h>
#include <stdint.h>

typedef __bf16  bf16x8 __attribute__((ext_vector_type(8)));
typedef float   f32x4  __attribute__((ext_vector_type(4)));
typedef unsigned short u16x8 __attribute__((ext_vector_type(8)));

__device__ __forceinline__ unsigned short f2bf(float f) {
  unsigned int u = __float_as_uint(f);
  u += 0x7fffu + ((u >> 16) & 1u);
  return (unsigned short)(u >> 16);
}
__device__ __forceinline__ float bflo(unsigned int v) { return __uint_as_float(v << 16); }
__device__ __forceinline__ float bfhi(unsigned int v) { return __uint_as_float(v & 0xffff0000u); }

// int64-vs-int32 edge detect, computed redundantly per thread (4 odd slots all
// zero <=> int64; node ids are random in [0,50000) so P(false)≈1.6e-19).
__device__ __forceinline__ int edges_are_i64(const int* __restrict__ eg) {
  return (eg[1] | eg[3] | eg[5] | eg[7]) == 0;
}

// ---------- fused: x->bf16 convert | weight prep | degree histogram ----------
__global__ void phase1_kernel(const float* __restrict__ x, unsigned short* __restrict__ A0, int n,
                              const int* __restrict__ eg, int* __restrict__ deg, int E,
                              const float* __restrict__ W00, const float* __restrict__ W10,
                              const float* __restrict__ W01, const float* __restrict__ W11,
                              const float* __restrict__ b00, const float* __restrict__ b10,
                              const float* __restrict__ b01, const float* __restrict__ b11,
                              unsigned short* __restrict__ Bt1, unsigned short* __restrict__ Bt2,
                              float* __restrict__ bias1, float* __restrict__ bias2) {
  const int i = blockIdx.x * 256 + threadIdx.x;
  if (i < n * 64) {
    const int row = i >> 6, c4 = i & 63;
    const float4 v = ((const float4*)x)[i];
    ushort4 o;
    o.x = f2bf(v.x); o.y = f2bf(v.y); o.z = f2bf(v.z); o.w = f2bf(v.w);
    *(ushort4*)&A0[(size_t)row * 512 + c4 * 4] = o;
  }
  if (i < 512 * 512) {
    const int nn = i >> 9, k = i & 511;
    const float v1 = (k < 256) ? W00[k * 512 + nn] : W10[(k - 256) * 512 + nn];
    Bt1[i] = f2bf(v1);
    const float v2 = (nn < 256) ? W01[k * 256 + nn] : W11[k * 256 + (nn - 256)];
    Bt2[i] = f2bf(v2);
    if (i < 512) {
      bias1[i] = b00[i] + b10[i];
      bias2[i] = (i < 256) ? (b01[i] + b11[i]) : 0.f;
    }
  }
  if (i < E) {
    int a, b;
    if (edges_are_i64(eg)) { a = eg[4 * i]; b = eg[4 * i + 2]; }
    else                   { a = eg[2 * i]; b = eg[2 * i + 1]; }
    if ((unsigned)a < (unsigned)n && (unsigned)b < (unsigned)n) {
      atomicAdd(&deg[a], 1);
      atomicAdd(&deg[b], 1);
    }
  }
}

// ---------- scan pass 1: per-block (1024) sums ----------
__global__ void block_sum_kernel(const int* __restrict__ deg, int* __restrict__ bsum, int n) {
  const int t = threadIdx.x;
  const int i = blockIdx.x * 1024 + t;
  int v = (i < n) ? deg[i] : 0;
  #pragma unroll
  for (int d = 32; d > 0; d >>= 1) v += __shfl_xor(v, d);
  __shared__ int ws[16];
  if ((t & 63) == 0) ws[t >> 6] = v;
  __syncthreads();
  if (t < 16) {
    int s = ws[t];
    #pragma unroll
    for (int d = 1; d < 16; d <<= 1) s += __shfl_xor(s, d);
    if (t == 0) bsum[blockIdx.x] = s;
  }
}

// ---------- scan pass 2: exclusive scan of block sums (<=64 blocks) ----------
__global__ void scan_bsum_kernel(int* __restrict__ bsum, int* __restrict__ off, int nb, int n) {
  const int l = threadIdx.x;
  int v = (l < nb) ? bsum[l] : 0;
  const int orig = v;
  #pragma unroll
  for (int d = 1; d < 64; d <<= 1) {
    int u = __shfl_up(v, d);
    if (l >= d) v += u;
  }
  if (l < nb) bsum[l] = v - orig;
  if (l == nb - 1) off[n] = v;
}

// ---------- scan pass 3: final offsets + invdeg + zero curp ----------
__global__ void scan_final_kernel(const int* __restrict__ deg, const int* __restrict__ bsum,
                                  int* __restrict__ off, float* __restrict__ invd,
                                  int* __restrict__ curp, int n) {
  const int t = threadIdx.x;
  const int i = blockIdx.x * 1024 + t;
  const int lane = t & 63, wid = t >> 6;
  const int v = (i < n) ? deg[i] : 0;
  int s = v;
  #pragma unroll
  for (int d = 1; d < 64; d <<= 1) {
    int u = __shfl_up(s, d);
    if (lane >= d) s += u;
  }
  __shared__ int ws[16];
  if (lane == 63) ws[wid] = s;
  __syncthreads();
  if (t < 16) {
    int w = ws[t];
    #pragma unroll
    for (int d = 1; d < 16; d <<= 1) {
      int u = __shfl_up(w, d);
      if (t >= d) w += u;
    }
    ws[t] = w;
  }
  __syncthreads();
  const int add = (wid > 0) ? ws[wid - 1] : 0;
  const int incl = s + add;
  if (i < n) {
    off[i] = bsum[blockIdx.x] + incl - v;
    invd[i] = 1.f / (float)(v > 1 ? v : 1);
    curp[i] = 0;
  }
}

// ---------- CSR fill ----------
__global__ void fill_kernel(const int* __restrict__ eg,
                            const int* __restrict__ off, int* __restrict__ cur,
                            int* __restrict__ adj, int E, int n) {
  const int e = blockIdx.x * 256 + threadIdx.x;
  if (e >= E) return;
  int a, b;
  if (edges_are_i64(eg)) { a = eg[4 * e]; b = eg[4 * e + 2]; }
  else                   { a = eg[2 * e]; b = eg[2 * e + 1]; }
  if ((unsigned)a >= (unsigned)n || (unsigned)b >= (unsigned)n) return;
  int p = atomicAdd(&cur[b], 1); adj[off[b] + p] = a;
  int q = atomicAdd(&cur[a], 1); adj[off[a] + q] = b;
}

// ---------- wide gather: one wave per dst node; 2 neighbor rows per uint4 load ----------
// MODE 0: A0 left half (stride 512) -> bf16 mean into A0 right half
// MODE 1: Z (stride 256) -> out += invd * sum (fp32 RMW; out holds self path P)
template<int MODE>
__global__ __launch_bounds__(256) void agg_wide_kernel(
    const unsigned short* __restrict__ T, unsigned short* A0w, float* out,
    const int* __restrict__ adj, const int* __restrict__ off,
    const float* __restrict__ invd, int n) {
  const int node = blockIdx.x * 4 + (threadIdx.x >> 6);
  if (node >= n) return;
  const int lane = threadIdx.x & 63;
  const int half = lane >> 5;
  const int cq = lane & 31;
  constexpr size_t RS = (MODE == 0) ? 512 : 256;
  const int s = off[node], e = off[node + 1];
  float a0 = 0.f, a1 = 0.f, a2 = 0.f, a3 = 0.f, a4 = 0.f, a5 = 0.f, a6 = 0.f, a7 = 0.f;
  for (int base = s; base < e; base += 64) {
    const int cnt = min(64, e - base);
    const int idxv = (lane < cnt) ? adj[base + lane] : 0;
    for (int j = 0; j < cnt; j += 8) {
      uint4 v0 = make_uint4(0u, 0u, 0u, 0u), v1 = v0, v2 = v0, v3 = v0;
      const int s0 = j + 0 + half, s1 = j + 2 + half, s2 = j + 4 + half, s3 = j + 6 + half;
      const int r0 = __shfl(idxv, s0), r1 = __shfl(idxv, s1);
      const int r2 = __shfl(idxv, s2), r3 = __shfl(idxv, s3);
      if (s0 < cnt) v0 = *(const uint4*)&T[(size_t)r0 * RS + cq * 8];
      if (s1 < cnt) v1 = *(const uint4*)&T[(size_t)r1 * RS + cq * 8];
      if (s2 < cnt) v2 = *(const uint4*)&T[(size_t)r2 * RS + cq * 8];
      if (s3 < cnt) v3 = *(const uint4*)&T[(size_t)r3 * RS + cq * 8];
      a0 += bflo(v0.x) + bflo(v1.x) + bflo(v2.x) + bflo(v3.x);
      a1 += bfhi(v0.x) + bfhi(v1.x) + bfhi(v2.x) + bfhi(v3.x);
      a2 += bflo(v0.y) + bflo(v1.y) + bflo(v2.y) + bflo(v3.y);
      a3 += bfhi(v0.y) + bfhi(v1.y) + bfhi(v2.y) + bfhi(v3.y);
      a4 += bflo(v0.z) + bflo(v1.z) + bflo(v2.z) + bflo(v3.z);
      a5 += bfhi(v0.z) + bfhi(v1.z) + bfhi(v2.z) + bfhi(v3.z);
      a6 += bflo(v0.w) + bflo(v1.w) + bflo(v2.w) + bflo(v3.w);
      a7 += bfhi(v0.w) + bfhi(v1.w) + bfhi(v2.w) + bfhi(v3.w);
    }
  }
  a0 += __shfl_xor(a0, 32); a1 += __shfl_xor(a1, 32);
  a2 += __shfl_xor(a2, 32); a3 += __shfl_xor(a3, 32);
  a4 += __shfl_xor(a4, 32); a5 += __shfl_xor(a5, 32);
  a6 += __shfl_xor(a6, 32); a7 += __shfl_xor(a7, 32);
  if (half == 0) {
    const float sc = invd[node];
    if (MODE == 0) {
      u16x8 o;
      o[0] = f2bf(a0 * sc); o[1] = f2bf(a1 * sc); o[2] = f2bf(a2 * sc); o[3] = f2bf(a3 * sc);
      o[4] = f2bf(a4 * sc); o[5] = f2bf(a5 * sc); o[6] = f2bf(a6 * sc); o[7] = f2bf(a7 * sc);
      *(u16x8*)&A0w[(size_t)node * 512 + 256 + cq * 8] = o;
    } else {
      float* po = &out[(size_t)node * 256 + cq * 8];
      float4 p0 = *(float4*)po;
      float4 p1 = *(float4*)(po + 4);
      p0.x += sc * a0; p0.y += sc * a1; p0.z += sc * a2; p0.w += sc * a3;
      p1.x += sc * a4; p1.y += sc * a5; p1.z += sc * a6; p1.w += sc * a7;
      *(float4*)po = p0;
      *(float4*)(po + 4) = p1;
    }
  }
}

// ---------- bf16 MFMA GEMM: C[M,512] = A[M,512] @ B[512,512]; B given as Bt[n][k] ----------
// Triple-buffered BK=32, counted vmcnt. CORRECTNESS CONTRACT: every stage's 4
// global_load_lds form one program-order group, pinned by volatile-asm +
// sched_barrier fences, so vmcnt(4k) identifies whole tiles. lgkmcnt(0) before
// the 2nd barrier closes the ds_read-vs-DMA-overwrite window. 48 KiB LDS.
// MODE 0: Hout = bf16(relu(C + bias[col]))
// MODE 1: n0<256 -> Pout fp32 = C + bias[col] (row<M guard); else Zout = bf16(C)
template<int MODE>
__global__ __launch_bounds__(256, 3) void gemm_kernel(
    const unsigned short* __restrict__ A, const unsigned short* __restrict__ Bt,
    const float* __restrict__ bias,
    unsigned short* __restrict__ Hout, float* __restrict__ Pout, unsigned short* __restrict__ Zout,
    int M_real, int nwg) {
  constexpr int K = 512;
  constexpr int BK = 32;
  constexpr int NT = K / BK;  // 16 K-tiles
  __shared__ unsigned short sm[6][128 * BK];  // A bufs sm[0..2], B bufs sm[3..5]
  const int t = threadIdx.x;
  const int lane = t & 63;
  const int wid = t >> 6;
  const int wr = wid >> 1;
  const int wc = wid & 1;

  const int orig = blockIdx.x;
  const int q = nwg >> 3, r = nwg & 7;
  const int xcd = orig & 7, bidx = orig >> 3;
  const int wgid = (xcd < r ? xcd * (q + 1) : r * (q + 1) + (xcd - r) * q) + bidx;
  const int m0 = (wgid >> 2) * 128;
  const int n0 = (wgid & 3) * 128;

  f32x4 acc[4][4];
  #pragma unroll
  for (int m = 0; m < 4; ++m)
    #pragma unroll
    for (int n = 0; n < 4; ++n)
      acc[m][n] = f32x4{0.f, 0.f, 0.f, 0.f};

  auto stage = [&](int buf, int kt) {
    #pragma unroll
    for (int i = 0; i < 2; ++i) {
      const int row = i * 64 + (t >> 2);
      const int c = (t & 3) ^ ((row >> 1) & 3);
      const unsigned short* ga = A + (size_t)(m0 + row) * K + kt * BK + c * 8;
      __builtin_amdgcn_global_load_lds(
          (const __attribute__((address_space(1))) unsigned int*)ga,
          (__attribute__((address_space(3))) unsigned int*)&sm[buf][(i * 256 + t) * 8], 16, 0, 0);
    }
    #pragma unroll
    for (int i = 0; i < 2; ++i) {
      const int row = i * 64 + (t >> 2);
      const int c = (t & 3) ^ ((row >> 1) & 3);
      const unsigned short* gb = Bt + (size_t)(n0 + row) * K + kt * BK + c * 8;
      __builtin_amdgcn_global_load_lds(
          (const __attribute__((address_space(1))) unsigned int*)gb,
          (__attribute__((address_space(3))) unsigned int*)&sm[3 + buf][(i * 256 + t) * 8], 16, 0, 0);
    }
    // pin this stage's 4 loads as one program-order group
    asm volatile("" ::: "memory");
    __builtin_amdgcn_sched_barrier(0);
  };

  auto compute = [&](int buf) {
    bf16x8 aF[4], bF[4];
    #pragma unroll
    for (int m = 0; m < 4; ++m) {
      const int row = wr * 64 + m * 16 + (lane & 15);
      const int sl = (lane >> 4) ^ ((row >> 1) & 3);
      aF[m] = *(const bf16x8*)&sm[buf][row * BK + sl * 8];
    }
    #pragma unroll
    for (int n = 0; n < 4; ++n) {
      const int row = wc * 64 + n * 16 + (lane & 15);
      const int sl = (lane >> 4) ^ ((row >> 1) & 3);
      bF[n] = *(const bf16x8*)&sm[3 + buf][row * BK + sl * 8];
    }
    #pragma unroll
    for (int m = 0; m < 4; ++m)
      #pragma unroll
      for (int n = 0; n < 4; ++n)
        acc[m][n] = __builtin_amdgcn_mfma_f32_16x16x32_bf16(aF[m], bF[n], acc[m][n], 0, 0, 0);
  };

  stage(0, 0);
  stage(1, 1);
  #pragma unroll 1
  for (int kt = 0; kt < NT; ++kt) {
    if (kt + 2 < NT) stage((kt + 2) % 3, kt + 2);
    // counted wait: tile kt's 4 loads (oldest group) landed; younger tiles stay in flight
    if (kt < NT - 2)       { asm volatile("s_waitcnt vmcnt(8)" ::: "memory"); }
    else if (kt == NT - 2) { asm volatile("s_waitcnt vmcnt(4)" ::: "memory"); }
    else                   { asm volatile("s_waitcnt vmcnt(0)" ::: "memory"); }
    __builtin_amdgcn_sched_barrier(0);
    __builtin_amdgcn_s_barrier();   // all waves' tile-kt loads landed
    __builtin_amdgcn_sched_barrier(0);
    compute(kt % 3);
    asm volatile("s_waitcnt lgkmcnt(0)" ::: "memory");  // my LDS reads of tile kt done
    __builtin_amdgcn_sched_barrier(0);
    __builtin_amdgcn_s_barrier();   // everyone done reading -> buf reusable for DMA
    __builtin_amdgcn_sched_barrier(0);
  }
  __syncthreads();  // full drain; LDS free for epilogue reuse

  if (MODE == 0 || n0 >= 256) {
    unsigned short* ep = &sm[0][0];
    #pragma unroll
    for (int n = 0; n < 4; ++n) {
      const int lcol = wc * 64 + n * 16 + (lane & 15);
      const float bc = (MODE == 0) ? bias[n0 + lcol] : 0.f;
      #pragma unroll
      for (int m = 0; m < 4; ++m) {
        #pragma unroll
        for (int rr = 0; rr < 4; ++rr) {
          const int lr = wr * 64 + m * 16 + (lane >> 4) * 4 + rr;
          float y = acc[m][n][rr] + bc;
          if (MODE == 0) y = y > 0.f ? y : 0.f;
          ep[lr * 128 + (lcol ^ (((lr >> 2) & 7) << 4))] = f2bf(y);
        }
      }
    }
    __syncthreads();
    unsigned short* dst = (MODE == 0) ? Hout : Zout;
    const int ld = (MODE == 0) ? 512 : 256;
    const int cb0 = (MODE == 0) ? n0 : (n0 - 256);
    #pragma unroll
    for (int p = 0; p < 8; ++p) {
      const int tr = p * 16 + (t >> 4);
      const int cb = (t & 15) * 8;
      const uint4 v = *(const uint4*)&ep[tr * 128 + (cb ^ (((tr >> 2) & 7) << 4))];
      *(uint4*)&dst[(size_t)(m0 + tr) * ld + cb0 + cb] = v;
    }
  } else {
    float* ep = (float*)&sm[0][0];
    #pragma unroll
    for (int pp = 0; pp < 2; ++pp) {
      if (wr == pp) {
        #pragma unroll
        for (int n = 0; n < 4; ++n) {
          const int lcol = wc * 64 + n * 16 + (lane & 15);
          const float bc = bias[n0 + lcol];
          #pragma unroll
          for (int m = 0; m < 4; ++m)
            #pragma unroll
            for (int rr = 0; rr < 4; ++rr) {
              const int lr = m * 16 + (lane >> 4) * 4 + rr;
              ep[lr * 128 + (lcol ^ (((lr >> 2) & 7) << 4))] = acc[m][n][rr] + bc;
            }
        }
      }
      __syncthreads();
      const int tr = t >> 2;
      const int grow = m0 + pp * 64 + tr;
      if (grow < M_real) {
        #pragma unroll
        for (int j = 0; j < 8; ++j) {
          const int cb = (t & 3) * 32 + j * 4;
          const float4 v = *(const float4*)&ep[tr * 128 + (cb ^ (((tr >> 2) & 7) << 4))];
          *(float4*)&Pout[(size_t)grow * 256 + n0 + cb] = v;
        }
      }
      __syncthreads();
    }
  }
}

extern "C" void kernel_launch(void* const* d_in, const int* in_sizes, int n_in,
                              void* d_out, int out_size, void* d_ws, size_t ws_size,
                              hipStream_t stream) {
  const float* x   = (const float*)d_in[0];
  const int* edges = (const int*)d_in[1];
  const float* W00 = (const float*)d_in[2];
  const float* b00 = (const float*)d_in[3];
  const float* W10 = (const float*)d_in[4];
  const float* b10 = (const float*)d_in[5];
  const float* W01 = (const float*)d_in[6];
  const float* b01 = (const float*)d_in[7];
  const float* W11 = (const float*)d_in[8];
  const float* b11 = (const float*)d_in[9];
  float* out = (float*)d_out;

  const int n = in_sizes[0] / 256;   // 50000 nodes
  const int E = in_sizes[1] / 2;     // 400000 edges
  const int Mpad = ((n + 127) / 128) * 128;

  char* p = (char*)d_ws;
  auto alloc = [&](size_t bytes) { char* r = p; p += (bytes + 255) & ~(size_t)255; return r; };
  unsigned short* A0   = (unsigned short*)alloc((size_t)Mpad * 512 * 2);
  unsigned short* H    = (unsigned short*)alloc((size_t)Mpad * 512 * 2);
  unsigned short* Z    = (unsigned short*)alloc((size_t)Mpad * 256 * 2);
  unsigned short* Bt1  = (unsigned short*)alloc(512 * 512 * 2);
  unsigned short* Bt2  = (unsigned short*)alloc(512 * 512 * 2);
  float* bias1 = (float*)alloc(512 * 4);
  float* bias2 = (float*)alloc(512 * 4);
  int*   deg   = (int*)alloc((size_t)n * 4);
  int*   curp  = (int*)alloc((size_t)n * 4);
  int*   off   = (int*)alloc((size_t)(n + 1) * 4);
  int*   bsum  = (int*)alloc(256 * 4);
  float* invd  = (float*)alloc((size_t)n * 4);
  int*   adj   = (int*)alloc((size_t)2 * E * 4);

  hipMemsetAsync(deg, 0, (size_t)n * 4, stream);

  const int p1_blocks = (n * 64 + 255) / 256;
  phase1_kernel<<<p1_blocks, 256, 0, stream>>>(x, A0, n, edges, deg, E,
                                               W00, W10, W01, W11, b00, b10, b01, b11,
                                               Bt1, Bt2, bias1, bias2);

  const int nb = (n + 1023) / 1024;
  block_sum_kernel<<<nb, 1024, 0, stream>>>(deg, bsum, n);
  scan_bsum_kernel<<<1, 64, 0, stream>>>(bsum, off, nb, n);
  scan_final_kernel<<<nb, 1024, 0, stream>>>(deg, bsum, off, invd, curp, n);
  fill_kernel<<<(E + 255) / 256, 256, 0, stream>>>(edges, off, curp, adj, E, n);

  agg_wide_kernel<0><<<(n + 3) / 4, 256, 0, stream>>>(A0, A0, nullptr, adj, off, invd, n);

  const int nwg = (Mpad / 128) * 4;
  gemm_kernel<0><<<nwg, 256, 0, stream>>>(A0, Bt1, bias1, H, nullptr, nullptr, n, nwg);
  gemm_kernel<1><<<nwg, 256, 0, stream>>>(H, Bt2, bias2, nullptr, out, Z, n, nwg);

  agg_wide_kernel<1><<<(n + 3) / 4, 256, 0, stream>>>(Z, nullptr, out, adj, off, invd, n);
}